// Round 9
// baseline (414.473 us; speedup 1.0000x reference)
//
#include <hip/hip_runtime.h>
#include <hip/hip_bf16.h>
#include <stdint.h>

typedef __attribute__((ext_vector_type(8))) short s16x8;
typedef __attribute__((ext_vector_type(4))) short s16x4;
typedef __attribute__((ext_vector_type(4))) float f32x4;

#define L_T 12
#define P_S 4
#define NMAT 16
#define MROWS 6304
#define PD 128
#define DT 768
#define DS 384
#define KSUB 16
#define NIT 12
#define NBLK 50

// ---- workspace byte offsets (16B aligned) ----
#define SPART_B 0            // 16*50*16384 f32 = 52,428,800
#define CS_B    52428800     // 2048 f32 (zeroed)
#define MU_B    52436992
#define COVB_B  52445184     // 16*16384 bf16
#define U_B     52969472
#define CROSS_B 53100544
#define GRAM_B  53101568
#define W_B     53102592
#define WBT_B   53103616
#define WBS_B   53300224

__device__ __forceinline__ short f2bf(float f) {
    __hip_bfloat16 h = __float2bfloat16(f);
    return *reinterpret_cast<short*>(&h);
}
__device__ __forceinline__ float bf2f(short s) {
    union { uint32_t u; float f; } c;
    c.u = ((uint32_t)(uint16_t)s) << 16;
    return c.f;
}

// ------------------------------------------------------------------
// K0: blocks [0,144): phi fp32->bf16; blocks [144,152): zero cs.
// ------------------------------------------------------------------
__global__ __launch_bounds__(256) void k_init(const float* __restrict__ phit,
                                              const float* __restrict__ phis,
                                              short* __restrict__ wbt,
                                              short* __restrict__ wbs,
                                              float* __restrict__ cs) {
    int b = blockIdx.x;
    if (b < 144) {
        int e = (b * 256 + threadIdx.x) * 4;
        const float* src; short* dst; int off;
        if (e < PD * DT) { src = phit; dst = wbt; off = e; }
        else             { src = phis; dst = wbs; off = e - PD * DT; }
        float4 v = *(const float4*)(src + off);
        s16x4 h;
        h[0] = f2bf(v.x); h[1] = f2bf(v.y); h[2] = f2bf(v.z); h[3] = f2bf(v.w);
        *(s16x4*)(dst + off) = h;
    } else {
        cs[(b - 144) * 256 + threadIdx.x] = 0.f;
    }
}

// ------------------------------------------------------------------
// K1: fused projection + covariance partials. grid (50,16), block 256.
// No LDS staging for the GEMM: A and W fragments are loaded directly
// from global in MFMA fragment layout (full-line coalesced; W is
// bf16 + L2-resident). No per-K-step barriers. Zs LDS only for the
// z^T z phase.
// ------------------------------------------------------------------
__global__ __launch_bounds__(256, 4) void k_zcov(const float* __restrict__ Tt,
                                                 const float* __restrict__ St,
                                                 const short* __restrict__ wbt,
                                                 const short* __restrict__ wbs,
                                                 float* __restrict__ spart,
                                                 float* __restrict__ cs_g) {
    __shared__ short Zs[128][136];   // 34816 B
    int mat = blockIdx.y;
    const float* A; const short* Wb; int D;
    if (mat < L_T) { A = Tt + (size_t)mat * MROWS * DT; Wb = wbt; D = DT; }
    else           { A = St + (size_t)(mat - L_T) * MROWS * DS; Wb = wbs; D = DS; }
    int m0 = blockIdx.x * 128;
    int tid = threadIdx.x;
    int wid = tid >> 6, lane = tid & 63;
    int rw = lane & 15, kb = lane >> 4;

    // per-lane A rows (2 fragments) and validity
    int mrow[2];
    mrow[0] = m0 + 32 * wid + rw;
    mrow[1] = mrow[0] + 16;
    const float* pa0 = A + (size_t)mrow[0] * D + kb * 8;
    const float* pa1 = A + (size_t)mrow[1] * D + kb * 8;
    bool ok0 = mrow[0] < MROWS, ok1 = mrow[1] < MROWS;
    const short* pw = Wb + rw * D + kb * 8;   // + 16c*D per c

    f32x4 acc[2][8];
#pragma unroll
    for (int r = 0; r < 2; r++)
#pragma unroll
        for (int c = 0; c < 8; c++) acc[r][c] = (f32x4){0.f, 0.f, 0.f, 0.f};

    for (int d0 = 0; d0 < D; d0 += 32) {
        s16x8 ah[2];
        {
            float4 v0 = make_float4(0.f,0.f,0.f,0.f), v1 = v0;
            if (ok0) { v0 = *(const float4*)(pa0 + d0); v1 = *(const float4*)(pa0 + d0 + 4); }
            ah[0][0] = f2bf(v0.x); ah[0][1] = f2bf(v0.y); ah[0][2] = f2bf(v0.z); ah[0][3] = f2bf(v0.w);
            ah[0][4] = f2bf(v1.x); ah[0][5] = f2bf(v1.y); ah[0][6] = f2bf(v1.z); ah[0][7] = f2bf(v1.w);
            if (ok1) { v0 = *(const float4*)(pa1 + d0); v1 = *(const float4*)(pa1 + d0 + 4); }
            else     { v0 = make_float4(0.f,0.f,0.f,0.f); v1 = v0; }
            ah[1][0] = f2bf(v0.x); ah[1][1] = f2bf(v0.y); ah[1][2] = f2bf(v0.z); ah[1][3] = f2bf(v0.w);
            ah[1][4] = f2bf(v1.x); ah[1][5] = f2bf(v1.y); ah[1][6] = f2bf(v1.z); ah[1][7] = f2bf(v1.w);
        }
#pragma unroll
        for (int c = 0; c < 8; c++) {
            s16x8 wv = *(const s16x8*)(pw + (size_t)(16 * c) * D + d0);
#pragma unroll
            for (int r = 0; r < 2; r++)
                acc[r][c] = __builtin_amdgcn_mfma_f32_16x16x32_bf16(ah[r], wv, acc[r][c], 0, 0, 0);
        }
    }
    // z-tile (bf16) -> LDS, layout Zs[q][m_local]
#pragma unroll
    for (int c = 0; c < 8; c++) {
        int q = 16 * c + rw;
#pragma unroll
        for (int r = 0; r < 2; r++) {
            s16x4 o;
            o[0] = f2bf(acc[r][c][0]); o[1] = f2bf(acc[r][c][1]);
            o[2] = f2bf(acc[r][c][2]); o[3] = f2bf(acc[r][c][3]);
            *(s16x4*)&Zs[q][32 * wid + 16 * r + 4 * kb] = o;
        }
    }
    __syncthreads();
    if (tid < 128) {
        float s = 0.f;
#pragma unroll
        for (int mm = 0; mm < 128; mm += 8) {
            s16x8 v = *(s16x8*)&Zs[tid][mm];
#pragma unroll
            for (int u = 0; u < 8; u++) s += bf2f(v[u]);
        }
        atomicAdd(cs_g + mat * PD + tid, s);
    }
    f32x4 a2[2][8];
#pragma unroll
    for (int r = 0; r < 2; r++)
#pragma unroll
        for (int cc = 0; cc < 8; cc++) a2[r][cc] = (f32x4){0.f, 0.f, 0.f, 0.f};
#pragma unroll
    for (int kc = 0; kc < 4; kc++) {
        s16x8 fr[8];
#pragma unroll
        for (int t = 0; t < 8; t++) fr[t] = *(s16x8*)&Zs[16 * t + rw][kc * 32 + kb * 8];
#pragma unroll
        for (int r = 0; r < 2; r++)
#pragma unroll
            for (int cc = 0; cc < 8; cc++)
                a2[r][cc] = __builtin_amdgcn_mfma_f32_16x16x32_bf16(
                    fr[2 * wid + r], fr[cc], a2[r][cc], 0, 0, 0);
    }
    float* sb = spart + ((size_t)mat * NBLK + blockIdx.x) * 16384;
#pragma unroll
    for (int r = 0; r < 2; r++)
#pragma unroll
        for (int cc = 0; cc < 8; cc++)
#pragma unroll
            for (int rr = 0; rr < 4; rr++) {
                int row = (2 * wid + r) * 16 + 4 * kb + rr;
                int col = 16 * cc + rw;
                sb[row * 128 + col] = a2[r][cc][rr];
            }
}

// ------------------------------------------------------------------
// K2: reduce S-partials, finalize cov -> bf16, write mu. grid (8,16).
// ------------------------------------------------------------------
__global__ __launch_bounds__(256) void k_covred(const float* __restrict__ spart,
                                                const float* __restrict__ cs_g,
                                                float* __restrict__ mu_g,
                                                short* __restrict__ covb) {
    int mat = blockIdx.y, seg = blockIdx.x;
    int tid = threadIdx.x;
    int e0 = (seg * 256 + tid) * 8;
    float s[8];
#pragma unroll
    for (int u = 0; u < 8; u++) s[u] = 0.f;
    const float* base = spart + (size_t)mat * NBLK * 16384 + e0;
    for (int b = 0; b < NBLK; b++) {
        const float* p = base + (size_t)b * 16384;
        float4 u0 = *(const float4*)(p);
        float4 u1 = *(const float4*)(p + 4);
        s[0] += u0.x; s[1] += u0.y; s[2] += u0.z; s[3] += u0.w;
        s[4] += u1.x; s[5] += u1.y; s[6] += u1.z; s[7] += u1.w;
    }
    int i = e0 >> 7, j0 = e0 & 127;
    float mi = cs_g[mat * PD + i] * (1.0f / MROWS);
    s16x8 o;
#pragma unroll
    for (int u = 0; u < 8; u++) {
        float mj = cs_g[mat * PD + j0 + u] * (1.0f / MROWS);
        o[u] = f2bf(s[u] * (1.0f / MROWS) - mi * mj);
    }
    *(s16x8*)(covb + (size_t)mat * 16384 + e0) = o;
    if (seg == 0 && tid < 128)
        mu_g[mat * PD + tid] = cs_g[mat * PD + tid] * (1.0f / MROWS);
}

// ------------------------------------------------------------------
// K3: top-16 invariant subspace. grid 16, block 512. NIT=12,
// CholQR at it 3,7,11 (final fp32).
// ------------------------------------------------------------------
__global__ __launch_bounds__(512) void k_eigen(const short* __restrict__ covb,
                                               float* __restrict__ U) {
    __shared__ short Abf[128][136];
    __shared__ short Qbf[2][16][136];
    __shared__ float Yt[16][132];
    __shared__ float G[16][17];
    __shared__ float Lc[16][17];
    __shared__ float rinvs[16];
    int mat = blockIdx.x, tid = threadIdx.x;
    int wid = tid >> 6, lane = tid & 63;
    int rw = lane & 15, kb = lane >> 4;
    {
        int row = tid >> 2, sg = (tid & 3) << 5;
        const short* src = covb + (size_t)mat * 16384 + row * 128 + sg;
#pragma unroll
        for (int k = 0; k < 4; k++)
            *(s16x8*)&Abf[row][sg + 8 * k] = *(const s16x8*)(src + 8 * k);
    }
    {
#pragma unroll
        for (int u = 0; u < 4; u++) {
            int e = tid * 4 + u;
            int j = e >> 7, m = e & 127;
            uint32_t x = (uint32_t)e ^ (0x9E3779B9u * (uint32_t)(mat + 1));
            x ^= x >> 16; x *= 0x7feb352du; x ^= x >> 15; x *= 0x846ca68bu; x ^= x >> 16;
            float v = (float)(int)x * 4.6566129e-10f;
            Qbf[0][j][m] = f2bf(v);
        }
    }
    __syncthreads();
    s16x8 areg[4];
#pragma unroll
    for (int kc = 0; kc < 4; kc++)
        areg[kc] = *(s16x8*)&Abf[16 * wid + rw][kc * 32 + kb * 8];

    int cur = 0;
    for (int it = 0; it < NIT; it++) {
        __syncthreads();
        f32x4 acc = (f32x4){0.f, 0.f, 0.f, 0.f};
#pragma unroll
        for (int kc = 0; kc < 4; kc++) {
            s16x8 b = *(s16x8*)&Qbf[cur][rw][kc * 32 + kb * 8];
            acc = __builtin_amdgcn_mfma_f32_16x16x32_bf16(areg[kc], b, acc, 0, 0, 0);
        }
        bool fin = (it == NIT - 1);
        bool orth = ((it & 3) == 3) || fin;
        if (!orth) {
            s16x4 sv;
            sv[0] = f2bf(acc[0]); sv[1] = f2bf(acc[1]);
            sv[2] = f2bf(acc[2]); sv[3] = f2bf(acc[3]);
            *(s16x4*)&Qbf[cur ^ 1][rw][16 * wid + 4 * kb] = sv;
            cur ^= 1;
        } else {
            *(f32x4*)&Yt[rw][16 * wid + 4 * kb] = acc;
            __syncthreads();
            if (tid < 256) {
                int i = tid >> 4, j = tid & 15;
                float s = 0.f;
                for (int mm = 0; mm < 128; mm += 4) {
                    float4 a = *(float4*)&Yt[i][mm];
                    float4 b = *(float4*)&Yt[j][mm];
                    s += a.x * b.x + a.y * b.y + a.z * b.z + a.w * b.w;
                }
                G[i][j] = s;
            }
            __syncthreads();
            if (tid < 16) {
                float g[16], Lr[16];
#pragma unroll
                for (int j = 0; j < 16; j++) g[j] = G[tid][j];
                float tr = g[tid];
#pragma unroll
                for (int off = 8; off > 0; off >>= 1) tr += __shfl_xor(tr, off);
                g[tid] += (fin ? 1e-6f : 0.03f) * (tr * (1.0f / 16.0f));
#pragma unroll
                for (int j = 0; j < 16; j++) {
                    float s = g[j];
#pragma unroll
                    for (int k = 0; k < j; k++) s -= Lr[k] * __shfl(Lr[k], j);
                    float dj = __shfl(s, j);
                    float d = sqrtf(fmaxf(dj, 1e-20f));
                    Lr[j] = (tid == j) ? d : ((tid > j) ? s / d : 0.f);
                }
#pragma unroll
                for (int j = 0; j < 16; j++) Lc[tid][j] = Lr[j];
                rinvs[tid] = 1.0f / Lc[tid][tid];
            }
            __syncthreads();
            if (tid < 128) {
                int m = tid;
                float q[16];
#pragma unroll
                for (int j = 0; j < 16; j++) {
                    float s = Yt[j][m];
#pragma unroll
                    for (int k = 0; k < j; k++) s -= Lc[j][k] * q[k];
                    q[j] = s * rinvs[j];
                }
                if (fin) {
                    float* ub = U + (size_t)mat * KSUB * PD;
#pragma unroll
                    for (int j = 0; j < 16; j++) ub[j * PD + m] = q[j];
                } else {
#pragma unroll
                    for (int j = 0; j < 16; j++) Qbf[cur ^ 1][j][m] = f2bf(q[j]);
                }
            }
            cur ^= 1;
        }
    }
}

// ------------------------------------------------------------------
// K4: pairwise ||U_a^T U_b||_F^2. grid 114, block 256.
// ------------------------------------------------------------------
__global__ __launch_bounds__(256) void k_gram(const float* __restrict__ U,
                                              float* __restrict__ cross,
                                              float* __restrict__ gram) {
    __shared__ float red[256];
    int bid = blockIdx.x;
    int ma, mb; bool isCross;
    if (bid < 66) {
        int a = 0, rem = bid;
        while (rem >= 11 - a) { rem -= 11 - a; a++; }
        ma = a; mb = a + 1 + rem; isCross = true;
    } else {
        int idx = bid - 66;
        ma = 12 + idx / 12; mb = idx % 12; isCross = false;
    }
    int tid = threadIdx.x;
    int i = tid >> 4, j = tid & 15;
    const float* ua = U + ((size_t)ma * KSUB + i) * PD;
    const float* ub = U + ((size_t)mb * KSUB + j) * PD;
    float s = 0.f;
    for (int m = 0; m < PD; m += 4) {
        float4 x = *(const float4*)(ua + m);
        float4 y = *(const float4*)(ub + m);
        s += x.x * y.x + x.y * y.y + x.z * y.z + x.w * y.w;
    }
    red[tid] = s * s;
    __syncthreads();
    for (int st = 128; st > 0; st >>= 1) {
        if (tid < st) red[tid] += red[tid + st];
        __syncthreads();
    }
    if (tid == 0) {
        if (isCross) { cross[ma * L_T + mb] = red[0]; cross[mb * L_T + ma] = red[0]; }
        else gram[(ma - 12) * L_T + mb] = red[0];
    }
}

// ------------------------------------------------------------------
// K5: softmax weights + reg_loss. 1 block, 128 threads.
// ------------------------------------------------------------------
__global__ __launch_bounds__(128) void k_weights(const float* __restrict__ gram,
                                                 const float* __restrict__ cross,
                                                 const float* __restrict__ mu,
                                                 const float* __restrict__ logt,
                                                 float* __restrict__ w,
                                                 float* __restrict__ loss_out) {
    __shared__ float wsm[P_S][L_T];
    __shared__ float red[128];
    int tid = threadIdx.x;
    if (tid < P_S) {
        float tau = log1pf(expf(logt[tid]));
        float x[L_T];
        float mx = -1e30f;
#pragma unroll
        for (int l = 0; l < L_T; l++) {
            float d = 1.0f - gram[tid * L_T + l] * (1.0f / 16.0f);
            x[l] = -d / tau;
            mx = fmaxf(mx, x[l]);
        }
        float ssum = 0.f;
#pragma unroll
        for (int l = 0; l < L_T; l++) { x[l] = expf(x[l] - mx); ssum += x[l]; }
        float inv = 1.0f / ssum;
#pragma unroll
        for (int l = 0; l < L_T; l++) { float wv = x[l] * inv; wsm[tid][l] = wv; w[tid * L_T + l] = wv; }
    }
    __syncthreads();
    float racc = 0.f;
    {
        int q = tid;
#pragma unroll
        for (int p = 0; p < P_S; p++) {
            float zm = 0.f;
#pragma unroll
            for (int l = 0; l < L_T; l++) zm += wsm[p][l] * mu[l * PD + q];
            float d = zm - mu[(12 + p) * PD + q];
            racc += d * d;
        }
    }
    red[tid] = racc;
    __syncthreads();
    for (int st = 64; st > 0; st >>= 1) {
        if (tid < st) red[tid] += red[tid + st];
        __syncthreads();
    }
    if (tid == 0) {
        float recon = red[0] * (1.0f / PD);
        float orth = 0.f;
        for (int p = 0; p < P_S; p++)
            for (int a = 0; a < L_T; a++)
                for (int b = 0; b < L_T; b++)
                    if (a != b) orth += wsm[p][a] * wsm[p][b] * cross[a * L_T + b];
        orth *= 0.5f;
        loss_out[0] = 0.01f * orth / P_S + 0.01f * recon / P_S;
    }
}

// ------------------------------------------------------------------
// K6: fused mix (teachers + attns), nontemporal streaming.
// ------------------------------------------------------------------
#define MIX_TB 1280
#define MIX_AB 3840
__global__ __launch_bounds__(256) void k_mix2(const float* __restrict__ Tt,
                                              const float* __restrict__ Ta,
                                              const float* __restrict__ w,
                                              float* __restrict__ outT,
                                              float* __restrict__ outA) {
    float wr[P_S][L_T];
#pragma unroll
    for (int p = 0; p < P_S; p++)
#pragma unroll
        for (int l = 0; l < L_T; l++) wr[p][l] = w[p * L_T + l];
    const float* in; float* out; size_t nl; int nv, v0, stride;
    if (blockIdx.x < MIX_TB) {
        in = Tt; out = outT; nl = (size_t)MROWS * DT;
        nv = (int)(nl / 4);
        v0 = blockIdx.x * 256 + threadIdx.x;
        stride = MIX_TB * 256;
    } else {
        in = Ta; out = outA; nl = (size_t)32 * 12 * 197 * 197;
        nv = (int)(nl / 4);
        v0 = (blockIdx.x - MIX_TB) * 256 + threadIdx.x;
        stride = MIX_AB * 256;
    }
    for (int v = v0; v < nv; v += stride) {
        f32x4 o[P_S];
#pragma unroll
        for (int p = 0; p < P_S; p++) o[p] = (f32x4){0.f, 0.f, 0.f, 0.f};
#pragma unroll
        for (int l = 0; l < L_T; l++) {
            f32x4 x = __builtin_nontemporal_load((const f32x4*)(in + (size_t)l * nl) + v);
#pragma unroll
            for (int p = 0; p < P_S; p++) {
                o[p][0] += wr[p][l] * x[0]; o[p][1] += wr[p][l] * x[1];
                o[p][2] += wr[p][l] * x[2]; o[p][3] += wr[p][l] * x[3];
            }
        }
#pragma unroll
        for (int p = 0; p < P_S; p++)
            __builtin_nontemporal_store(o[p], (f32x4*)(out + (size_t)p * nl) + v);
    }
}

extern "C" void kernel_launch(void* const* d_in, const int* in_sizes, int n_in,
                              void* d_out, int out_size, void* d_ws, size_t ws_size,
                              hipStream_t stream) {
    const float* student  = (const float*)d_in[0];
    const float* teacherT = (const float*)d_in[1];
    const float* teacherA = (const float*)d_in[2];
    const float* phis     = (const float*)d_in[3];
    const float* phit     = (const float*)d_in[4];
    const float* logt     = (const float*)d_in[5];
    float* out = (float*)d_out;

    char* ws = (char*)d_ws;
    float* spart = (float*)(ws + SPART_B);
    float* cs_g  = (float*)(ws + CS_B);
    float* mu    = (float*)(ws + MU_B);
    short* covb  = (short*)(ws + COVB_B);
    float* U     = (float*)(ws + U_B);
    float* cross = (float*)(ws + CROSS_B);
    float* gram  = (float*)(ws + GRAM_B);
    float* w     = (float*)(ws + W_B);
    short* wbt   = (short*)(ws + WBT_B);
    short* wbs   = (short*)(ws + WBS_B);

    k_init<<<152, 256, 0, stream>>>(phit, phis, wbt, wbs, cs_g);
    k_zcov<<<dim3(NBLK, 16), 256, 0, stream>>>(teacherT, student, wbt, wbs, spart, cs_g);
    k_covred<<<dim3(8, 16), 256, 0, stream>>>(spart, cs_g, mu, covb);
    k_eigen<<<16, 512, 0, stream>>>(covb, U);
    k_gram<<<114, 256, 0, stream>>>(U, cross, gram);
    k_weights<<<1, 128, 0, stream>>>(gram, cross, mu, logt, w, out + 78976512);
    k_mix2<<<MIX_TB + MIX_AB, 256, 0, stream>>>(teacherT, teacherA, w,
                                                out, out + 19365888);
}

// Round 10
// 387.451 us; speedup vs baseline: 1.0697x; 1.0697x over previous
//
#include <hip/hip_runtime.h>
#include <hip/hip_bf16.h>
#include <stdint.h>

typedef __attribute__((ext_vector_type(8))) short s16x8;
typedef __attribute__((ext_vector_type(4))) short s16x4;
typedef __attribute__((ext_vector_type(4))) float f32x4;

#define L_T 12
#define P_S 4
#define NMAT 16
#define MROWS 6304
#define PD 128
#define DT 768
#define DS 384
#define KSUB 16
#define NIT 12
#define NBLK 50

// ---- workspace byte offsets (16B aligned) ----
#define SPART_B 0            // 16*50*16384 f32 = 52,428,800
#define CS_B    52428800     // 2048 f32 (zeroed)
#define MU_B    52436992
#define COVB_B  52445184     // 16*16384 bf16
#define U_B     52969472
#define CROSS_B 53100544
#define GRAM_B  53101568
#define W_B     53102592
#define WBT_B   53103616
#define WBS_B   53300224

__device__ __forceinline__ short f2bf(float f) {
    __hip_bfloat16 h = __float2bfloat16(f);
    return *reinterpret_cast<short*>(&h);
}
__device__ __forceinline__ float bf2f(short s) {
    union { uint32_t u; float f; } c;
    c.u = ((uint32_t)(uint16_t)s) << 16;
    return c.f;
}

// ------------------------------------------------------------------
// K0: blocks [0,144): phi fp32->bf16; blocks [144,152): zero cs.
// ------------------------------------------------------------------
__global__ __launch_bounds__(256) void k_init(const float* __restrict__ phit,
                                              const float* __restrict__ phis,
                                              short* __restrict__ wbt,
                                              short* __restrict__ wbs,
                                              float* __restrict__ cs) {
    int b = blockIdx.x;
    if (b < 144) {
        int e = (b * 256 + threadIdx.x) * 4;
        const float* src; short* dst; int off;
        if (e < PD * DT) { src = phit; dst = wbt; off = e; }
        else             { src = phis; dst = wbs; off = e - PD * DT; }
        float4 v = *(const float4*)(src + off);
        s16x4 h;
        h[0] = f2bf(v.x); h[1] = f2bf(v.y); h[2] = f2bf(v.z); h[3] = f2bf(v.w);
        *(s16x4*)(dst + off) = h;
    } else {
        cs[(b - 144) * 256 + threadIdx.x] = 0.f;
    }
}

// ------------------------------------------------------------------
// K1: fused projection + covariance partials. grid (50,16), block 256.
// (R8 version — LDS staged GEMM, Zs overlay, 4 blocks/CU.)
// ------------------------------------------------------------------
__global__ __launch_bounds__(256, 4) void k_zcov(const float* __restrict__ Tt,
                                                 const float* __restrict__ St,
                                                 const short* __restrict__ wbt,
                                                 const short* __restrict__ wbs,
                                                 float* __restrict__ spart,
                                                 float* __restrict__ cs_g) {
    __shared__ char smem[128 * 136 * 2];                 // 34816 B
    short (*As)[40] = (short(*)[40])smem;                // 10240 B
    short (*Ws)[40] = (short(*)[40])(smem + 10240);      // 10240 B
    short (*Zs)[136] = (short(*)[136])smem;              // aliases As+Ws
    int mat = blockIdx.y;
    const float* A; const short* Wb; int D;
    if (mat < L_T) { A = Tt + (size_t)mat * MROWS * DT; Wb = wbt; D = DT; }
    else           { A = St + (size_t)(mat - L_T) * MROWS * DS; Wb = wbs; D = DS; }
    int m0 = blockIdx.x * 128;
    int tid = threadIdx.x;
    int wid = tid >> 6, lane = tid & 63;
    int rw = lane & 15, kb = lane >> 4;
    f32x4 acc[2][8];
#pragma unroll
    for (int r = 0; r < 2; r++)
#pragma unroll
        for (int c = 0; c < 8; c++) acc[r][c] = (f32x4){0.f, 0.f, 0.f, 0.f};

    for (int d0 = 0; d0 < D; d0 += 32) {
        __syncthreads();
#pragma unroll
        for (int ii = 0; ii < 4; ii++) {
            int f = tid + 256 * ii;
            int row = f >> 3, c4 = (f & 7) << 2;
            int m = m0 + row;
            float4 v = make_float4(0.f, 0.f, 0.f, 0.f);
            if (m < MROWS) v = *(const float4*)(A + (size_t)m * D + d0 + c4);
            s16x4 h;
            h[0] = f2bf(v.x); h[1] = f2bf(v.y); h[2] = f2bf(v.z); h[3] = f2bf(v.w);
            *(s16x4*)&As[row][c4] = h;
        }
#pragma unroll
        for (int ii = 0; ii < 2; ii++) {
            int f = tid + 256 * ii;
            int row = f >> 2, c8 = (f & 3) << 3;
            *(s16x8*)&Ws[row][c8] = *(const s16x8*)(Wb + (size_t)row * D + d0 + c8);
        }
        __syncthreads();
        s16x8 ah[2];
#pragma unroll
        for (int r = 0; r < 2; r++)
            ah[r] = *(s16x8*)&As[32 * wid + 16 * r + rw][kb * 8];
#pragma unroll
        for (int c = 0; c < 8; c++) {
            s16x8 wv = *(s16x8*)&Ws[16 * c + rw][kb * 8];
#pragma unroll
            for (int r = 0; r < 2; r++)
                acc[r][c] = __builtin_amdgcn_mfma_f32_16x16x32_bf16(ah[r], wv, acc[r][c], 0, 0, 0);
        }
    }
    __syncthreads();   // GEMM phase done; safe to overwrite As/Ws with Zs
#pragma unroll
    for (int c = 0; c < 8; c++) {
        int q = 16 * c + rw;
#pragma unroll
        for (int r = 0; r < 2; r++) {
            s16x4 o;
            o[0] = f2bf(acc[r][c][0]); o[1] = f2bf(acc[r][c][1]);
            o[2] = f2bf(acc[r][c][2]); o[3] = f2bf(acc[r][c][3]);
            *(s16x4*)&Zs[q][32 * wid + 16 * r + 4 * kb] = o;
        }
    }
    __syncthreads();
    if (tid < 128) {
        float s = 0.f;
#pragma unroll
        for (int mm = 0; mm < 128; mm += 8) {
            s16x8 v = *(s16x8*)&Zs[tid][mm];
#pragma unroll
            for (int u = 0; u < 8; u++) s += bf2f(v[u]);
        }
        atomicAdd(cs_g + mat * PD + tid, s);
    }
    f32x4 a2[2][8];
#pragma unroll
    for (int r = 0; r < 2; r++)
#pragma unroll
        for (int cc = 0; cc < 8; cc++) a2[r][cc] = (f32x4){0.f, 0.f, 0.f, 0.f};
#pragma unroll
    for (int kc = 0; kc < 4; kc++) {
        s16x8 fr[8];
#pragma unroll
        for (int t = 0; t < 8; t++) fr[t] = *(s16x8*)&Zs[16 * t + rw][kc * 32 + kb * 8];
#pragma unroll
        for (int r = 0; r < 2; r++)
#pragma unroll
            for (int cc = 0; cc < 8; cc++)
                a2[r][cc] = __builtin_amdgcn_mfma_f32_16x16x32_bf16(
                    fr[2 * wid + r], fr[cc], a2[r][cc], 0, 0, 0);
    }
    float* sb = spart + ((size_t)mat * NBLK + blockIdx.x) * 16384;
#pragma unroll
    for (int r = 0; r < 2; r++)
#pragma unroll
        for (int cc = 0; cc < 8; cc++)
#pragma unroll
            for (int rr = 0; rr < 4; rr++) {
                int row = (2 * wid + r) * 16 + 4 * kb + rr;
                int col = 16 * cc + rw;
                sb[row * 128 + col] = a2[r][cc][rr];
            }
}

// ------------------------------------------------------------------
// K2: reduce S-partials, finalize cov -> bf16, write mu. grid (8,16).
// ------------------------------------------------------------------
__global__ __launch_bounds__(256) void k_covred(const float* __restrict__ spart,
                                                const float* __restrict__ cs_g,
                                                float* __restrict__ mu_g,
                                                short* __restrict__ covb) {
    int mat = blockIdx.y, seg = blockIdx.x;
    int tid = threadIdx.x;
    int e0 = (seg * 256 + tid) * 8;
    float s[8];
#pragma unroll
    for (int u = 0; u < 8; u++) s[u] = 0.f;
    const float* base = spart + (size_t)mat * NBLK * 16384 + e0;
    for (int b = 0; b < NBLK; b++) {
        const float* p = base + (size_t)b * 16384;
        float4 u0 = *(const float4*)(p);
        float4 u1 = *(const float4*)(p + 4);
        s[0] += u0.x; s[1] += u0.y; s[2] += u0.z; s[3] += u0.w;
        s[4] += u1.x; s[5] += u1.y; s[6] += u1.z; s[7] += u1.w;
    }
    int i = e0 >> 7, j0 = e0 & 127;
    float mi = cs_g[mat * PD + i] * (1.0f / MROWS);
    s16x8 o;
#pragma unroll
    for (int u = 0; u < 8; u++) {
        float mj = cs_g[mat * PD + j0 + u] * (1.0f / MROWS);
        o[u] = f2bf(s[u] * (1.0f / MROWS) - mi * mj);
    }
    *(s16x8*)(covb + (size_t)mat * 16384 + e0) = o;
    if (seg == 0 && tid < 128)
        mu_g[mat * PD + tid] = cs_g[mat * PD + tid] * (1.0f / MROWS);
}

// ------------------------------------------------------------------
// K3: top-16 invariant subspace. grid 16, block 512. NIT=12,
// CholQR at it 3,7,11 (final fp32).
// ------------------------------------------------------------------
__global__ __launch_bounds__(512) void k_eigen(const short* __restrict__ covb,
                                               float* __restrict__ U) {
    __shared__ short Abf[128][136];
    __shared__ short Qbf[2][16][136];
    __shared__ float Yt[16][132];
    __shared__ float G[16][17];
    __shared__ float Lc[16][17];
    __shared__ float rinvs[16];
    int mat = blockIdx.x, tid = threadIdx.x;
    int wid = tid >> 6, lane = tid & 63;
    int rw = lane & 15, kb = lane >> 4;
    {
        int row = tid >> 2, sg = (tid & 3) << 5;
        const short* src = covb + (size_t)mat * 16384 + row * 128 + sg;
#pragma unroll
        for (int k = 0; k < 4; k++)
            *(s16x8*)&Abf[row][sg + 8 * k] = *(const s16x8*)(src + 8 * k);
    }
    {
#pragma unroll
        for (int u = 0; u < 4; u++) {
            int e = tid * 4 + u;
            int j = e >> 7, m = e & 127;
            uint32_t x = (uint32_t)e ^ (0x9E3779B9u * (uint32_t)(mat + 1));
            x ^= x >> 16; x *= 0x7feb352du; x ^= x >> 15; x *= 0x846ca68bu; x ^= x >> 16;
            float v = (float)(int)x * 4.6566129e-10f;
            Qbf[0][j][m] = f2bf(v);
        }
    }
    __syncthreads();
    s16x8 areg[4];
#pragma unroll
    for (int kc = 0; kc < 4; kc++)
        areg[kc] = *(s16x8*)&Abf[16 * wid + rw][kc * 32 + kb * 8];

    int cur = 0;
    for (int it = 0; it < NIT; it++) {
        __syncthreads();
        f32x4 acc = (f32x4){0.f, 0.f, 0.f, 0.f};
#pragma unroll
        for (int kc = 0; kc < 4; kc++) {
            s16x8 b = *(s16x8*)&Qbf[cur][rw][kc * 32 + kb * 8];
            acc = __builtin_amdgcn_mfma_f32_16x16x32_bf16(areg[kc], b, acc, 0, 0, 0);
        }
        bool fin = (it == NIT - 1);
        bool orth = ((it & 3) == 3) || fin;
        if (!orth) {
            s16x4 sv;
            sv[0] = f2bf(acc[0]); sv[1] = f2bf(acc[1]);
            sv[2] = f2bf(acc[2]); sv[3] = f2bf(acc[3]);
            *(s16x4*)&Qbf[cur ^ 1][rw][16 * wid + 4 * kb] = sv;
            cur ^= 1;
        } else {
            *(f32x4*)&Yt[rw][16 * wid + 4 * kb] = acc;
            __syncthreads();
            if (tid < 256) {
                int i = tid >> 4, j = tid & 15;
                float s = 0.f;
                for (int mm = 0; mm < 128; mm += 4) {
                    float4 a = *(float4*)&Yt[i][mm];
                    float4 b = *(float4*)&Yt[j][mm];
                    s += a.x * b.x + a.y * b.y + a.z * b.z + a.w * b.w;
                }
                G[i][j] = s;
            }
            __syncthreads();
            if (tid < 16) {
                float g[16], Lr[16];
#pragma unroll
                for (int j = 0; j < 16; j++) g[j] = G[tid][j];
                float tr = g[tid];
#pragma unroll
                for (int off = 8; off > 0; off >>= 1) tr += __shfl_xor(tr, off);
                g[tid] += (fin ? 1e-6f : 0.03f) * (tr * (1.0f / 16.0f));
#pragma unroll
                for (int j = 0; j < 16; j++) {
                    float s = g[j];
#pragma unroll
                    for (int k = 0; k < j; k++) s -= Lr[k] * __shfl(Lr[k], j);
                    float dj = __shfl(s, j);
                    float d = sqrtf(fmaxf(dj, 1e-20f));
                    Lr[j] = (tid == j) ? d : ((tid > j) ? s / d : 0.f);
                }
#pragma unroll
                for (int j = 0; j < 16; j++) Lc[tid][j] = Lr[j];
                rinvs[tid] = 1.0f / Lc[tid][tid];
            }
            __syncthreads();
            if (tid < 128) {
                int m = tid;
                float q[16];
#pragma unroll
                for (int j = 0; j < 16; j++) {
                    float s = Yt[j][m];
#pragma unroll
                    for (int k = 0; k < j; k++) s -= Lc[j][k] * q[k];
                    q[j] = s * rinvs[j];
                }
                if (fin) {
                    float* ub = U + (size_t)mat * KSUB * PD;
#pragma unroll
                    for (int j = 0; j < 16; j++) ub[j * PD + m] = q[j];
                } else {
#pragma unroll
                    for (int j = 0; j < 16; j++) Qbf[cur ^ 1][j][m] = f2bf(q[j]);
                }
            }
            cur ^= 1;
        }
    }
}

// ------------------------------------------------------------------
// K4: pairwise ||U_a^T U_b||_F^2. grid 114, block 256.
// ------------------------------------------------------------------
__global__ __launch_bounds__(256) void k_gram(const float* __restrict__ U,
                                              float* __restrict__ cross,
                                              float* __restrict__ gram) {
    __shared__ float red[256];
    int bid = blockIdx.x;
    int ma, mb; bool isCross;
    if (bid < 66) {
        int a = 0, rem = bid;
        while (rem >= 11 - a) { rem -= 11 - a; a++; }
        ma = a; mb = a + 1 + rem; isCross = true;
    } else {
        int idx = bid - 66;
        ma = 12 + idx / 12; mb = idx % 12; isCross = false;
    }
    int tid = threadIdx.x;
    int i = tid >> 4, j = tid & 15;
    const float* ua = U + ((size_t)ma * KSUB + i) * PD;
    const float* ub = U + ((size_t)mb * KSUB + j) * PD;
    float s = 0.f;
    for (int m = 0; m < PD; m += 4) {
        float4 x = *(const float4*)(ua + m);
        float4 y = *(const float4*)(ub + m);
        s += x.x * y.x + x.y * y.y + x.z * y.z + x.w * y.w;
    }
    red[tid] = s * s;
    __syncthreads();
    for (int st = 128; st > 0; st >>= 1) {
        if (tid < st) red[tid] += red[tid + st];
        __syncthreads();
    }
    if (tid == 0) {
        if (isCross) { cross[ma * L_T + mb] = red[0]; cross[mb * L_T + ma] = red[0]; }
        else gram[(ma - 12) * L_T + mb] = red[0];
    }
}

// ------------------------------------------------------------------
// K5: softmax weights + reg_loss. 1 block, 128 threads.
// ------------------------------------------------------------------
__global__ __launch_bounds__(128) void k_weights(const float* __restrict__ gram,
                                                 const float* __restrict__ cross,
                                                 const float* __restrict__ mu,
                                                 const float* __restrict__ logt,
                                                 float* __restrict__ w,
                                                 float* __restrict__ loss_out) {
    __shared__ float wsm[P_S][L_T];
    __shared__ float red[128];
    int tid = threadIdx.x;
    if (tid < P_S) {
        float tau = log1pf(expf(logt[tid]));
        float x[L_T];
        float mx = -1e30f;
#pragma unroll
        for (int l = 0; l < L_T; l++) {
            float d = 1.0f - gram[tid * L_T + l] * (1.0f / 16.0f);
            x[l] = -d / tau;
            mx = fmaxf(mx, x[l]);
        }
        float ssum = 0.f;
#pragma unroll
        for (int l = 0; l < L_T; l++) { x[l] = expf(x[l] - mx); ssum += x[l]; }
        float inv = 1.0f / ssum;
#pragma unroll
        for (int l = 0; l < L_T; l++) { float wv = x[l] * inv; wsm[tid][l] = wv; w[tid * L_T + l] = wv; }
    }
    __syncthreads();
    float racc = 0.f;
    {
        int q = tid;
#pragma unroll
        for (int p = 0; p < P_S; p++) {
            float zm = 0.f;
#pragma unroll
            for (int l = 0; l < L_T; l++) zm += wsm[p][l] * mu[l * PD + q];
            float d = zm - mu[(12 + p) * PD + q];
            racc += d * d;
        }
    }
    red[tid] = racc;
    __syncthreads();
    for (int st = 64; st > 0; st >>= 1) {
        if (tid < st) red[tid] += red[tid + st];
        __syncthreads();
    }
    if (tid == 0) {
        float recon = red[0] * (1.0f / PD);
        float orth = 0.f;
        for (int p = 0; p < P_S; p++)
            for (int a = 0; a < L_T; a++)
                for (int b = 0; b < L_T; b++)
                    if (a != b) orth += wsm[p][a] * wsm[p][b] * cross[a * L_T + b];
        orth *= 0.5f;
        loss_out[0] = 0.01f * orth / P_S + 0.01f * recon / P_S;
    }
}

// ------------------------------------------------------------------
// K6a: teacher-token mix — TEMPORAL loads (teacherT should be
// L3-resident from k_zcov's read). grid 2048.
// ------------------------------------------------------------------
__global__ __launch_bounds__(256) void k_mixT(const float* __restrict__ in,
                                              const float* __restrict__ w,
                                              float* __restrict__ out) {
    const size_t nl = (size_t)MROWS * DT;
    const int nv = (int)(nl / 4);
    float wr[P_S][L_T];
#pragma unroll
    for (int p = 0; p < P_S; p++)
#pragma unroll
        for (int l = 0; l < L_T; l++) wr[p][l] = w[p * L_T + l];
    int stride = gridDim.x * blockDim.x;
    for (int v = blockIdx.x * 256 + threadIdx.x; v < nv; v += stride) {
        f32x4 o[P_S];
#pragma unroll
        for (int p = 0; p < P_S; p++) o[p] = (f32x4){0.f, 0.f, 0.f, 0.f};
#pragma unroll
        for (int l = 0; l < L_T; l++) {
            f32x4 x = *((const f32x4*)(in + (size_t)l * nl) + v);
#pragma unroll
            for (int p = 0; p < P_S; p++) {
                o[p][0] += wr[p][l] * x[0]; o[p][1] += wr[p][l] * x[1];
                o[p][2] += wr[p][l] * x[2]; o[p][3] += wr[p][l] * x[3];
            }
        }
#pragma unroll
        for (int p = 0; p < P_S; p++)
            __builtin_nontemporal_store(o[p], (f32x4*)(out + (size_t)p * nl) + v);
    }
}

// ------------------------------------------------------------------
// K6b: attention mix — nontemporal streaming. grid 4096.
// ------------------------------------------------------------------
__global__ __launch_bounds__(256) void k_mixA(const float* __restrict__ in,
                                              const float* __restrict__ w,
                                              float* __restrict__ out) {
    const size_t nl = (size_t)32 * 12 * 197 * 197;
    const int nv = (int)(nl / 4);
    float wr[P_S][L_T];
#pragma unroll
    for (int p = 0; p < P_S; p++)
#pragma unroll
        for (int l = 0; l < L_T; l++) wr[p][l] = w[p * L_T + l];
    int stride = gridDim.x * blockDim.x;
    for (int v = blockIdx.x * 256 + threadIdx.x; v < nv; v += stride) {
        f32x4 o[P_S];
#pragma unroll
        for (int p = 0; p < P_S; p++) o[p] = (f32x4){0.f, 0.f, 0.f, 0.f};
#pragma unroll
        for (int l = 0; l < L_T; l++) {
            f32x4 x = __builtin_nontemporal_load((const f32x4*)(in + (size_t)l * nl) + v);
#pragma unroll
            for (int p = 0; p < P_S; p++) {
                o[p][0] += wr[p][l] * x[0]; o[p][1] += wr[p][l] * x[1];
                o[p][2] += wr[p][l] * x[2]; o[p][3] += wr[p][l] * x[3];
            }
        }
#pragma unroll
        for (int p = 0; p < P_S; p++)
            __builtin_nontemporal_store(o[p], (f32x4*)(out + (size_t)p * nl) + v);
    }
}

extern "C" void kernel_launch(void* const* d_in, const int* in_sizes, int n_in,
                              void* d_out, int out_size, void* d_ws, size_t ws_size,
                              hipStream_t stream) {
    const float* student  = (const float*)d_in[0];
    const float* teacherT = (const float*)d_in[1];
    const float* teacherA = (const float*)d_in[2];
    const float* phis     = (const float*)d_in[3];
    const float* phit     = (const float*)d_in[4];
    const float* logt     = (const float*)d_in[5];
    float* out = (float*)d_out;

    char* ws = (char*)d_ws;
    float* spart = (float*)(ws + SPART_B);
    float* cs_g  = (float*)(ws + CS_B);
    float* mu    = (float*)(ws + MU_B);
    short* covb  = (short*)(ws + COVB_B);
    float* U     = (float*)(ws + U_B);
    float* cross = (float*)(ws + CROSS_B);
    float* gram  = (float*)(ws + GRAM_B);
    float* w     = (float*)(ws + W_B);
    short* wbt   = (short*)(ws + WBT_B);
    short* wbs   = (short*)(ws + WBS_B);

    k_init<<<152, 256, 0, stream>>>(phit, phis, wbt, wbs, cs_g);
    k_zcov<<<dim3(NBLK, 16), 256, 0, stream>>>(teacherT, student, wbt, wbs, spart, cs_g);
    k_covred<<<dim3(8, 16), 256, 0, stream>>>(spart, cs_g, mu, covb);
    k_eigen<<<16, 512, 0, stream>>>(covb, U);
    k_gram<<<114, 256, 0, stream>>>(U, cross, gram);
    k_weights<<<1, 128, 0, stream>>>(gram, cross, mu, logt, w, out + 78976512);
    k_mixT<<<2048, 256, 0, stream>>>(teacherT, w, out);
    k_mixA<<<4096, 256, 0, stream>>>(teacherA, w, out + 19365888);
}